// Round 16
// baseline (353.901 us; speedup 1.0000x reference)
//
#include <hip/hip_runtime.h>
#include <hip/hip_bf16.h>
#include <stdint.h>

#define D_DIM 1024
#define P_ROWS 8192
#define K_ROWS 131072
#define M_DIM 512
#define L_STEPS 64

typedef short bf16x8_t __attribute__((ext_vector_type(8)));
typedef float f32x4_t __attribute__((ext_vector_type(4)));

typedef const __attribute__((address_space(1))) void* gas_t;
typedef __attribute__((address_space(3))) void* las_t;

__device__ __forceinline__ uint32_t f2bf(float f) {
  union { float f; uint32_t u; } c; c.f = f;
  const uint32_t u = c.u;
  return (u + 0x7FFFu + ((u >> 16) & 1u)) >> 16;   // RNE
}
__device__ __forceinline__ float bf2f(ushort s) {
  union { uint32_t u; float f; } c; c.u = ((uint32_t)s) << 16; return c.f;
}

// v[d] += sum_i y[i] * X[i,d]
__global__ void xty_kernel(const float* __restrict__ X, const float* __restrict__ y,
                           float* __restrict__ v) {
  const int d0 = threadIdx.x * 4;
  float a0 = 0.f, a1 = 0.f, a2 = 0.f, a3 = 0.f;
  for (int i = blockIdx.x; i < P_ROWS; i += gridDim.x) {
    const float s = y[i];
    const float4 x = *reinterpret_cast<const float4*>(X + (size_t)i * D_DIM + d0);
    a0 += s * x.x; a1 += s * x.y; a2 += s * x.z; a3 += s * x.w;
  }
  atomicAdd(v + d0 + 0, a0);
  atomicAdd(v + d0 + 1, a1);
  atomicAdd(v + d0 + 2, a2);
  atomicAdd(v + d0 + 3, a3);
}

// wout[d] += sum_i (X[i,:].win) * X[i,d]
__global__ void xtxw_kernel(const float* __restrict__ X, const float* __restrict__ win,
                            float* __restrict__ wout) {
  __shared__ float red[4][D_DIM];
  const int lane = threadIdx.x & 63;
  const int wave = threadIdx.x >> 6;
  const int gw = blockIdx.x * 4 + wave;
  const int nw = gridDim.x * 4;
  float wv[16], acc[16];
#pragma unroll
  for (int q = 0; q < 4; ++q) {
    const float4 tv = *reinterpret_cast<const float4*>(win + q * 256 + lane * 4);
    wv[q*4+0] = tv.x; wv[q*4+1] = tv.y; wv[q*4+2] = tv.z; wv[q*4+3] = tv.w;
  }
#pragma unroll
  for (int j = 0; j < 16; ++j) acc[j] = 0.f;
  for (int i = gw; i < P_ROWS; i += nw) {
    const float* xr = X + (size_t)i * D_DIM;
    float xv[16];
    float dot = 0.f;
#pragma unroll
    for (int q = 0; q < 4; ++q) {
      const float4 tv = *reinterpret_cast<const float4*>(xr + q * 256 + lane * 4);
      xv[q*4+0] = tv.x; xv[q*4+1] = tv.y; xv[q*4+2] = tv.z; xv[q*4+3] = tv.w;
      dot += tv.x * wv[q*4+0] + tv.y * wv[q*4+1] + tv.z * wv[q*4+2] + tv.w * wv[q*4+3];
    }
#pragma unroll
    for (int m = 1; m < 64; m <<= 1) dot += __shfl_xor(dot, m);
#pragma unroll
    for (int j = 0; j < 16; ++j) acc[j] += dot * xv[j];
  }
#pragma unroll
  for (int q = 0; q < 4; ++q) {
    float4 tv;
    tv.x = acc[q*4+0]; tv.y = acc[q*4+1]; tv.z = acc[q*4+2]; tv.w = acc[q*4+3];
    *reinterpret_cast<float4*>(&red[wave][q * 256 + lane * 4]) = tv;
  }
  __syncthreads();
  const int d0 = threadIdx.x * 4;
#pragma unroll
  for (int j = 0; j < 4; ++j)
    atomicAdd(wout + d0 + j, red[0][d0+j] + red[1][d0+j] + red[2][d0+j] + red[3][d0+j]);
}

// rep = gamma*(64 v - 2016 eps u1/P + 41664 eps^2 u2/P^2); emit rep/(L*P) and rep/||rep||
__global__ void combine_kernel(const float* __restrict__ v, const float* __restrict__ u1,
                               const float* __restrict__ u2, const float* __restrict__ gamma_p,
                               float* __restrict__ rep_lin, float* __restrict__ repn) {
  __shared__ float sred[4];
  const float gamma = *gamma_p;
  const float eps = gamma / (float)L_STEPS;
  const float c1 = 2016.0f * eps / (float)P_ROWS;
  const float c2 = 41664.0f * eps * eps / ((float)P_ROWS * (float)P_ROWS);
  const int d0 = threadIdx.x * 4;
  float r[4];
  float ss = 0.f;
#pragma unroll
  for (int j = 0; j < 4; ++j) {
    const float val = gamma * ((float)L_STEPS * v[d0+j] - c1 * u1[d0+j] + c2 * u2[d0+j]);
    r[j] = val;
    ss += val * val;
  }
#pragma unroll
  for (int m = 1; m < 64; m <<= 1) ss += __shfl_xor(ss, m);
  if ((threadIdx.x & 63) == 0) sred[threadIdx.x >> 6] = ss;
  __syncthreads();
  const float norm = sqrtf(sred[0] + sred[1] + sred[2] + sred[3]);
  const float inv_norm = 1.0f / (norm + 1e-8f);
  const float lin_s = 1.0f / ((float)L_STEPS * (float)P_ROWS);
#pragma unroll
  for (int j = 0; j < 4; ++j) {
    rep_lin[d0+j] = r[j] * lin_s;
    repn[d0+j]    = r[j] * inv_norm;
  }
}

// WnF fragment-major: byte addr (s*32+f)*1024 + l*16 holds bf16 x8 of
// W[f*16+(l&15)][s*32+(l>>4)*8 + 0..7] * repn[...]
__global__ void wn_frag_kernel(const float* __restrict__ W, const float* __restrict__ repn,
                               ushort* __restrict__ WnF) {
  const int gid = blockIdx.x * 256 + threadIdx.x;   // 65536
  const int l = gid & 63;
  const int f = (gid >> 6) & 31;
  const int s = gid >> 11;
  const int m = f * 16 + (l & 15);
  const int d0 = s * 32 + ((l >> 4) << 3);
  const float4 w0 = *reinterpret_cast<const float4*>(W + (size_t)m * D_DIM + d0);
  const float4 w1 = *reinterpret_cast<const float4*>(W + (size_t)m * D_DIM + d0 + 4);
  const float4 r0 = *reinterpret_cast<const float4*>(repn + d0);
  const float4 r1 = *reinterpret_cast<const float4*>(repn + d0 + 4);
  uint4 o;
  o.x = f2bf(w0.x*r0.x) | (f2bf(w0.y*r0.y) << 16);
  o.y = f2bf(w0.z*r0.z) | (f2bf(w0.w*r0.w) << 16);
  o.z = f2bf(w1.x*r1.x) | (f2bf(w1.y*r1.y) << 16);
  o.w = f2bf(w1.z*r1.z) | (f2bf(w1.w*r1.w) << 16);
  *reinterpret_cast<uint4*>(WnF + (size_t)gid * 8) = o;
}

__global__ void init_out_kernel(float* __restrict__ out, const float* __restrict__ b2p) {
  const int i = blockIdx.x * 256 + threadIdx.x;
  const float b2 = *b2p;
  float4 v; v.x = b2; v.y = b2; v.z = b2; v.w = b2;
  *reinterpret_cast<float4*>(out + (size_t)i * 4) = v;
}

// Fused GEMM, round 16: 256x256 tile, 1 block/CU, 8 waves (2wm x 4wn), BK=32.
// All LDS fragment-major & lane-linear (0 bank conflicts by construction).
// A: f32 global->reg (plain loads, 1-ahead), cvt->bf16 ds_write, 2-buf.
// B: global_load_lds from fragment-major WnF, 3-buf, staged 2-ahead.
// Single s_barrier/step; NO manual vmcnt: compiler's precise reg-dep wait for
// the held A f32 regs retires B(s+1) in-order and leaves B(s+2) in flight
// across the barrier. Grid 1024 = 512 m-tiles x 2 n-tiles, XCD-paired so both
// n-tiles of an m-panel share an XCD's L2 (A HBM read stays ~512 MB).
__global__ __launch_bounds__(512, 1)
void fused_kernel(const float* __restrict__ Xs, const ushort* __restrict__ WnF,
                  const float* __restrict__ rep_lin, const float* __restrict__ b1,
                  const float* __restrict__ aw, float* __restrict__ out) {
  __shared__ __align__(16) char ldsA[2][16384];
  __shared__ __align__(16) char ldsB[3][16384];
  __shared__ __align__(16) float lds_rep[D_DIM];
  __shared__ float mlp_acc[256];
  __shared__ float lin_acc[256];

  const int t = threadIdx.x;
  const int lane = t & 63;
  const int w = t >> 6;
  const int wm = w >> 2;
  const int wn = w & 3;
  const int fr = lane & 15;
  const int kg = lane >> 4;

  const int h = blockIdx.x;
  const int xcd = h & 7;
  const int jb = h >> 3;
  const int nhalf = jb & 1;
  const int mt = xcd + 8 * (jb >> 1);
  const size_t blockRow = (size_t)mt * 256;
  const int fbase = nhalf * 16;

  const int mfs = t >> 5;
  const int jj = t & 31;
  const int r0 = mfs * 16 + ((2 * jj) & 15);
  const int col8 = (jj >> 3) * 8;
  const float* gA0 = Xs + (blockRow + (size_t)r0) * D_DIM + col8;
  const float* gA1 = gA0 + D_DIM;
  const int awoff = mfs * 1024 + jj * 32;

  const char* gBw = (const char*)WnF + (size_t)(fbase + 2 * w) * 1024 + (size_t)lane * 16;
  const int bwoff = 2 * w * 1024;

  const int aoff = (wm * 8) * 1024 + lane * 16;
  const int boff = (wn * 4) * 1024 + lane * 16;
  const int loff = 2 * w * 1024 + lane * 16;
  const int roff = kg * 32;

  auto stageB = [&](int s) {
    char* d = &ldsB[0][0] + (s % 3) * 16384 + bwoff;
    const char* src = gBw + (size_t)s * 32768;
    __builtin_amdgcn_global_load_lds((gas_t)src, (las_t)d, 16, 0, 0);
    __builtin_amdgcn_global_load_lds((gas_t)(src + 1024), (las_t)(d + 1024), 16, 0, 0);
  };
  auto packA = [&](float4 x0, float4 x1, float4 x2, float4 x3, char* d) {
    uint4 v0, v1;
    v0.x = f2bf(x0.x) | (f2bf(x0.y) << 16); v0.y = f2bf(x0.z) | (f2bf(x0.w) << 16);
    v0.z = f2bf(x1.x) | (f2bf(x1.y) << 16); v0.w = f2bf(x1.z) | (f2bf(x1.w) << 16);
    v1.x = f2bf(x2.x) | (f2bf(x2.y) << 16); v1.y = f2bf(x2.z) | (f2bf(x2.w) << 16);
    v1.z = f2bf(x3.x) | (f2bf(x3.y) << 16); v1.w = f2bf(x3.z) | (f2bf(x3.w) << 16);
    *reinterpret_cast<uint4*>(d) = v0;
    *reinterpret_cast<uint4*>(d + 16) = v1;
  };

  f32x4_t acc[8][4];
#pragma unroll
  for (int mi = 0; mi < 8; ++mi)
#pragma unroll
    for (int ni = 0; ni < 4; ++ni)
      acc[mi][ni] = f32x4_t{0.f, 0.f, 0.f, 0.f};
  float lin0 = 0.f, lin1 = 0.f;

  // ---- prologue ----
  lds_rep[t] = rep_lin[t];
  lds_rep[t + 512] = rep_lin[t + 512];
  if (t < 256) { mlp_acc[t] = 0.f; lin_acc[t] = 0.f; }
  stageB(0); stageB(1);
  float4 a00 = *reinterpret_cast<const float4*>(gA0);
  float4 a01 = *reinterpret_cast<const float4*>(gA0 + 4);
  float4 a10 = *reinterpret_cast<const float4*>(gA1);
  float4 a11 = *reinterpret_cast<const float4*>(gA1 + 4);
  packA(a00, a01, a10, a11, &ldsA[0][0] + awoff);
  a00 = *reinterpret_cast<const float4*>(gA0 + 32);
  a01 = *reinterpret_cast<const float4*>(gA0 + 36);
  a10 = *reinterpret_cast<const float4*>(gA1 + 32);
  a11 = *reinterpret_cast<const float4*>(gA1 + 36);
  asm volatile("s_waitcnt lgkmcnt(0)" ::: "memory");
  __builtin_amdgcn_s_barrier();
  __builtin_amdgcn_sched_barrier(0);

  // ---- main loop: steps 0..30 ----
  for (int s = 0; s < 31; ++s) {
    const int p = s & 1;
    const char* Ab = &ldsA[0][0] + p * 16384;
    const char* Bb = &ldsB[0][0] + (s % 3) * 16384;
    if (s < 30) stageB(s + 2);
    bf16x8_t afr[8], bfr[4];
#pragma unroll
    for (int mi = 0; mi < 8; ++mi)
      afr[mi] = *reinterpret_cast<const bf16x8_t*>(Ab + aoff + mi * 1024);
#pragma unroll
    for (int ni = 0; ni < 4; ++ni)
      bfr[ni] = *reinterpret_cast<const bf16x8_t*>(Bb + boff + ni * 1024);
    const bf16x8_t lf0 = *reinterpret_cast<const bf16x8_t*>(Ab + loff);
    const bf16x8_t lf1 = *reinterpret_cast<const bf16x8_t*>(Ab + loff + 1024);
    {
      const char* rb = (const char*)lds_rep + s * 128 + roff;
      const f32x4_t rp0 = *reinterpret_cast<const f32x4_t*>(rb);
      const f32x4_t rp1 = *reinterpret_cast<const f32x4_t*>(rb + 16);
      const ushort* u0 = (const ushort*)&lf0;
      const ushort* u1 = (const ushort*)&lf1;
#pragma unroll
      for (int j = 0; j < 4; ++j) {
        lin0 += bf2f(u0[j]) * rp0[j] + bf2f(u0[j + 4]) * rp1[j];
        lin1 += bf2f(u1[j]) * rp0[j] + bf2f(u1[j + 4]) * rp1[j];
      }
    }
#pragma unroll
    for (int mi = 0; mi < 8; ++mi)
#pragma unroll
      for (int ni = 0; ni < 4; ++ni)
        acc[mi][ni] = __builtin_amdgcn_mfma_f32_16x16x32_bf16(afr[mi], bfr[ni], acc[mi][ni], 0, 0, 0);
    packA(a00, a01, a10, a11, &ldsA[0][0] + (p ^ 1) * 16384 + awoff);
    if (s < 30) {
      const float* pa0 = gA0 + (s + 2) * 32;
      const float* pa1 = gA1 + (s + 2) * 32;
      a00 = *reinterpret_cast<const float4*>(pa0);
      a01 = *reinterpret_cast<const float4*>(pa0 + 4);
      a10 = *reinterpret_cast<const float4*>(pa1);
      a11 = *reinterpret_cast<const float4*>(pa1 + 4);
    }
    asm volatile("s_waitcnt lgkmcnt(0)" ::: "memory");
    __builtin_amdgcn_s_barrier();
    __builtin_amdgcn_sched_barrier(0);
  }
  // ---- step 31 ----
  {
    const char* Ab = &ldsA[0][0] + 16384;
    const char* Bb = &ldsB[0][0] + 16384;
    bf16x8_t afr[8], bfr[4];
#pragma unroll
    for (int mi = 0; mi < 8; ++mi)
      afr[mi] = *reinterpret_cast<const bf16x8_t*>(Ab + aoff + mi * 1024);
#pragma unroll
    for (int ni = 0; ni < 4; ++ni)
      bfr[ni] = *reinterpret_cast<const bf16x8_t*>(Bb + boff + ni * 1024);
    const bf16x8_t lf0 = *reinterpret_cast<const bf16x8_t*>(Ab + loff);
    const bf16x8_t lf1 = *reinterpret_cast<const bf16x8_t*>(Ab + loff + 1024);
    {
      const char* rb = (const char*)lds_rep + 31 * 128 + roff;
      const f32x4_t rp0 = *reinterpret_cast<const f32x4_t*>(rb);
      const f32x4_t rp1 = *reinterpret_cast<const f32x4_t*>(rb + 16);
      const ushort* u0 = (const ushort*)&lf0;
      const ushort* u1 = (const ushort*)&lf1;
#pragma unroll
      for (int j = 0; j < 4; ++j) {
        lin0 += bf2f(u0[j]) * rp0[j] + bf2f(u0[j + 4]) * rp1[j];
        lin1 += bf2f(u1[j]) * rp0[j] + bf2f(u1[j + 4]) * rp1[j];
      }
    }
#pragma unroll
    for (int mi = 0; mi < 8; ++mi)
#pragma unroll
      for (int ni = 0; ni < 4; ++ni)
        acc[mi][ni] = __builtin_amdgcn_mfma_f32_16x16x32_bf16(afr[mi], bfr[ni], acc[mi][ni], 0, 0, 0);
  }

  // ---- epilogue ----
  float b1r[4], ar[4];
#pragma unroll
  for (int ni = 0; ni < 4; ++ni) {
    const int c = nhalf * 256 + wn * 64 + ni * 16 + fr;
    b1r[ni] = b1[c];
    ar[ni]  = aw[c];
  }
#pragma unroll
  for (int mi = 0; mi < 8; ++mi) {
#pragma unroll
    for (int r = 0; r < 4; ++r) {
      float sum = 0.f;
#pragma unroll
      for (int ni = 0; ni < 4; ++ni) {
        const float hv = acc[mi][ni][r] + b1r[ni];
        sum += fmaxf(hv, 0.f) * ar[ni];
      }
      sum += __shfl_xor(sum, 1);
      sum += __shfl_xor(sum, 2);
      sum += __shfl_xor(sum, 4);
      sum += __shfl_xor(sum, 8);
      if (fr == 0) {
        const int row = wm * 128 + mi * 16 + kg * 4 + r;
        atomicAdd(&mlp_acc[row], sum);
      }
    }
  }
  lin0 += __shfl_xor(lin0, 16); lin0 += __shfl_xor(lin0, 32);
  lin1 += __shfl_xor(lin1, 16); lin1 += __shfl_xor(lin1, 32);
  if (lane < 16) {
    lin_acc[(2 * w) * 16 + lane]     = lin0;
    lin_acc[(2 * w + 1) * 16 + lane] = lin1;
  }
  __syncthreads();
  if (t < 256) {
    const float add = mlp_acc[t] + (nhalf == 0 ? lin_acc[t] : 0.f);
    atomicAdd(out + blockRow + t, add);
  }
}

extern "C" void kernel_launch(void* const* d_in, const int* in_sizes, int n_in,
                              void* d_out, int out_size, void* d_ws, size_t ws_size,
                              hipStream_t stream) {
  const float* X     = (const float*)d_in[0];
  const float* y     = (const float*)d_in[1];
  const float* Xs    = (const float*)d_in[2];
  const float* gamma = (const float*)d_in[3];
  const float* W     = (const float*)d_in[4];
  const float* a     = (const float*)d_in[5];
  const float* b1    = (const float*)d_in[6];
  const float* b2    = (const float*)d_in[7];
  float* out = (float*)d_out;

  char* ws = (char*)d_ws;
  float*  v       = (float*)(ws + 0);
  float*  u1      = (float*)(ws + 4096);
  float*  u2      = (float*)(ws + 8192);
  float*  rep_lin = (float*)(ws + 12288);
  float*  repn    = (float*)(ws + 16384);
  ushort* WnF     = (ushort*)(ws + 20480);

  hipMemsetAsync(ws, 0, 3 * 4096, stream);
  hipLaunchKernelGGL(xty_kernel,      dim3(256), dim3(256), 0, stream, X, y, v);
  hipLaunchKernelGGL(xtxw_kernel,     dim3(256), dim3(256), 0, stream, X, v, u1);
  hipLaunchKernelGGL(xtxw_kernel,     dim3(256), dim3(256), 0, stream, X, u1, u2);
  hipLaunchKernelGGL(combine_kernel,  dim3(1),   dim3(256), 0, stream, v, u1, u2, gamma, rep_lin, repn);
  hipLaunchKernelGGL(wn_frag_kernel,  dim3(256), dim3(256), 0, stream, W, repn, WnF);
  hipLaunchKernelGGL(init_out_kernel, dim3(128), dim3(256), 0, stream, out, b2);
  hipLaunchKernelGGL(fused_kernel,    dim3(1024), dim3(512), 0, stream,
                     Xs, WnF, rep_lin, b1, a, out);
}